// Round 3
// baseline (89.020 us; speedup 1.0000x reference)
//
#include <hip/hip_runtime.h>
#include <hip/hip_bf16.h>

// VLAD pooling: B=16, S=H*W=1024, D=512, KC=12, K=10.
// ALL tensors fp32 (reference dtype; harness passes float32 as const float*).

#define B_   16
#define S_   1024
#define D_   512
#define KC_  12
#define K_   10
#define CH_  32            // s-chunks per batch (streaming path)
#define SCH_ (S_ / CH_)    // 32 pixels per chunk
#define NT1  128           // accum threads: 128 * 4 floats = 512 = D

// ---------------- streaming path (needs ~10.6 MB workspace) ----------------
// part:      [B][CH][K][D]  fp32 partial cluster sums
// asum_part: [B][CH][K]     fp32 partial softmax-weight sums
__global__ __launch_bounds__(NT1) void vlad_accum(
    const float* __restrict__ feat, const float* __restrict__ score,
    float* __restrict__ part, float* __restrict__ asum_part)
{
    const int bid = blockIdx.x;
    const int b = bid / CH_, c = bid % CH_;
    const int s0 = c * SCH_;
    const int tid = threadIdx.x;

    __shared__ float A[SCH_][KC_];   // rows are 48B -> 16B-aligned

    // --- softmax for this chunk's pixels (one pixel per thread, tid<32) ---
    if (tid < SCH_) {
        const int s = s0 + tid;
        const float4* sp = (const float4*)(score + (size_t)(b * S_ + s) * KC_);
        const float4 w0 = sp[0], w1 = sp[1], w2 = sp[2];
        float x[KC_] = {w0.x, w0.y, w0.z, w0.w, w1.x, w1.y, w1.z, w1.w,
                        w2.x, w2.y, w2.z, w2.w};
        float m = x[0];
        #pragma unroll
        for (int k = 1; k < KC_; k++) m = fmaxf(m, x[k]);
        float sum = 0.f;
        #pragma unroll
        for (int k = 0; k < KC_; k++) { x[k] = __expf(x[k] - m); sum += x[k]; }
        const float inv = 1.0f / sum;
        #pragma unroll
        for (int k = 0; k < KC_; k++) A[tid][k] = x[k] * inv;
    }
    __syncthreads();

    if (tid < K_) {
        float v = 0.f;
        #pragma unroll
        for (int s = 0; s < SCH_; s++) v += A[s][tid];
        asum_part[(b * CH_ + c) * K_ + tid] = v;
    }

    // --- main accumulation: thread owns d in [4*tid, 4*tid+4) ---
    float acc[K_][4];
    #pragma unroll
    for (int k = 0; k < K_; k++)
        acc[k][0] = acc[k][1] = acc[k][2] = acc[k][3] = 0.f;

    const float4* fp = (const float4*)(feat + (size_t)(b * S_ + s0) * D_) + tid;
    #pragma unroll 8
    for (int s = 0; s < SCH_; s++) {
        const float4 v = fp[s * (D_ / 4)];
        const float4 a0 = *(const float4*)(&A[s][0]);   // broadcast reads
        const float4 a1 = *(const float4*)(&A[s][4]);
        const float2 a2 = *(const float2*)(&A[s][8]);
        const float a[K_] = {a0.x, a0.y, a0.z, a0.w, a1.x, a1.y, a1.z, a1.w,
                             a2.x, a2.y};
        #pragma unroll
        for (int k = 0; k < K_; k++) {
            acc[k][0] += a[k] * v.x;
            acc[k][1] += a[k] * v.y;
            acc[k][2] += a[k] * v.z;
            acc[k][3] += a[k] * v.w;
        }
    }

    float* pp = part + ((size_t)(b * CH_ + c) * K_) * D_ + tid * 4;
    #pragma unroll
    for (int k = 0; k < K_; k++)
        *(float4*)(pp + k * D_) =
            make_float4(acc[k][0], acc[k][1], acc[k][2], acc[k][3]);
}

// One block per (b,k): reduce chunks, subtract asum*cluster, L2-normalize row.
__global__ __launch_bounds__(256) void vlad_final(
    const float* __restrict__ part, const float* __restrict__ asum_part,
    const float* __restrict__ cluster, float* __restrict__ out)
{
    const int b = blockIdx.x / K_;
    const int k = blockIdx.x % K_;
    const int tid = threadIdx.x;
    const int d = tid * 2;

    float s0 = 0.f, s1 = 0.f;
    #pragma unroll
    for (int c = 0; c < CH_; c++) {
        const float2 v = *(const float2*)(
            part + ((size_t)(b * CH_ + c) * K_ + k) * D_ + d);
        s0 += v.x; s1 += v.y;
    }
    float asv = 0.f;
    #pragma unroll
    for (int c = 0; c < CH_; c++) asv += asum_part[(b * CH_ + c) * K_ + k];

    const float2 cv = *(const float2*)(cluster + (size_t)k * D_ + d);
    const float r0 = s0 - asv * cv.x;
    const float r1 = s1 - asv * cv.y;

    float sq = r0 * r0 + r1 * r1;
    #pragma unroll
    for (int off = 32; off > 0; off >>= 1) sq += __shfl_down(sq, off, 64);
    __shared__ float wsum[4];
    const int lane = tid & 63, wid = tid >> 6;
    if (lane == 0) wsum[wid] = sq;
    __syncthreads();
    const float tot = wsum[0] + wsum[1] + wsum[2] + wsum[3];
    const float scale = rsqrtf(fmaxf(tot, 1e-12f));

    *(float2*)(out + (size_t)(b * K_ + k) * D_ + d) =
        make_float2(r0 * scale, r1 * scale);
}

// ---------------- ws-free fallback: one block per (b,k) ----------------
__global__ __launch_bounds__(256) void vlad_fused(
    const float* __restrict__ feat, const float* __restrict__ score,
    const float* __restrict__ cluster, float* __restrict__ out)
{
    const int b = blockIdx.x / K_;
    const int k = blockIdx.x % K_;
    const int tid = threadIdx.x;

    __shared__ float As[S_];
    __shared__ float red[128][4];
    __shared__ float scr[4];

    float pasum = 0.f;
    #pragma unroll
    for (int j = 0; j < S_ / 256; j++) {
        const int s = tid + j * 256;
        const float4* sp = (const float4*)(score + (size_t)(b * S_ + s) * KC_);
        const float4 w0 = sp[0], w1 = sp[1], w2 = sp[2];
        float x[KC_] = {w0.x, w0.y, w0.z, w0.w, w1.x, w1.y, w1.z, w1.w,
                        w2.x, w2.y, w2.z, w2.w};
        float m = x[0];
        #pragma unroll
        for (int i = 1; i < KC_; i++) m = fmaxf(m, x[i]);
        float sum = 0.f;
        #pragma unroll
        for (int i = 0; i < KC_; i++) sum += __expf(x[i] - m);
        const float a = __expf(x[k] - m) / sum;
        As[s] = a;
        pasum += a;
    }
    #pragma unroll
    for (int off = 32; off > 0; off >>= 1) pasum += __shfl_down(pasum, off, 64);
    if ((tid & 63) == 0) scr[tid >> 6] = pasum;
    __syncthreads();
    const float asum = scr[0] + scr[1] + scr[2] + scr[3];

    const int rh  = tid >> 7;        // wave-uniform row parity
    const int col = tid & 127;       // float4 group within D
    float a0 = 0.f, a1 = 0.f, a2 = 0.f, a3 = 0.f;
    const float4* fp = (const float4*)(feat + (size_t)b * S_ * D_) + col;
    #pragma unroll 8
    for (int i = 0; i < S_ / 2; i++) {
        const int s = 2 * i + rh;
        const float4 v = fp[(size_t)s * (D_ / 4)];
        const float a = As[s];
        a0 += a * v.x; a1 += a * v.y; a2 += a * v.z; a3 += a * v.w;
    }
    if (rh) { red[col][0] = a0; red[col][1] = a1; red[col][2] = a2; red[col][3] = a3; }
    __syncthreads();

    float r0 = 0.f, r1 = 0.f, r2 = 0.f, r3 = 0.f;
    float psq = 0.f;
    if (!rh) {
        const float4 cv = *((const float4*)(cluster + (size_t)k * D_) + col);
        r0 = a0 + red[col][0] - asum * cv.x;
        r1 = a1 + red[col][1] - asum * cv.y;
        r2 = a2 + red[col][2] - asum * cv.z;
        r3 = a3 + red[col][3] - asum * cv.w;
        psq = r0 * r0 + r1 * r1 + r2 * r2 + r3 * r3;
    }
    #pragma unroll
    for (int off = 32; off > 0; off >>= 1) psq += __shfl_down(psq, off, 64);
    if ((tid & 63) == 0) scr[tid >> 6] = psq;
    __syncthreads();
    const float tot = scr[0] + scr[1] + scr[2] + scr[3];
    const float scale = rsqrtf(fmaxf(tot, 1e-12f));

    if (!rh) {
        *((float4*)(out + (size_t)(b * K_ + k) * D_) + col) =
            make_float4(r0 * scale, r1 * scale, r2 * scale, r3 * scale);
    }
}

extern "C" void kernel_launch(void* const* d_in, const int* in_sizes, int n_in,
                              void* d_out, int out_size, void* d_ws, size_t ws_size,
                              hipStream_t stream) {
    const float* feat    = (const float*)d_in[0];
    const float* score   = (const float*)d_in[1];
    const float* cluster = (const float*)d_in[2];
    float* out = (float*)d_out;

    const size_t need = ((size_t)B_ * CH_ * K_ * D_ + (size_t)B_ * CH_ * K_)
                        * sizeof(float);
    if (ws_size >= need) {
        float* part      = (float*)d_ws;
        float* asum_part = part + (size_t)B_ * CH_ * K_ * D_;
        vlad_accum<<<B_ * CH_, NT1, 0, stream>>>(feat, score, part, asum_part);
        vlad_final<<<B_ * K_, 256, 0, stream>>>(part, asum_part, cluster, out);
    } else {
        vlad_fused<<<B_ * K_, 256, 0, stream>>>(feat, score, cluster, out);
    }
}

// Round 4
// 82.213 us; speedup vs baseline: 1.0828x; 1.0828x over previous
//
#include <hip/hip_runtime.h>
#include <hip/hip_bf16.h>

// VLAD pooling: B=16, S=H*W=1024, D=512, KC=12, K=10. All fp32.
// Kernel 1: grid B*CH blocks x 256 thr (2 s-parities x 128 d-cols),
//           partials part[B][K][CH][D] fp32 + asum_part[B][CH][K].
// Kernel 2: grid B*K blocks x 256 thr: reduce CH, subtract asum*cluster,
//           L2-normalize, store.

#define B_   16
#define S_   1024
#define D_   512
#define KC_  12
#define K_   10
#define CH_  32            // s-chunks per batch
#define SCH_ (S_ / CH_)    // 32 pixels per chunk
#define NT1  256

__global__ __launch_bounds__(NT1) void vlad_accum(
    const float* __restrict__ feat, const float* __restrict__ score,
    float* __restrict__ part, float* __restrict__ asum_part)
{
    const int bid = blockIdx.x;
    const int b = bid / CH_, c = bid % CH_;
    const int s0 = c * SCH_;
    const int tid = threadIdx.x;
    const int par = tid >> 7;     // wave-uniform s-parity
    const int col = tid & 127;    // float4 group within D

    __shared__ float A[SCH_][KC_];     // softmax weights, rows 48B
    __shared__ float red[K_ * 4][128]; // parity-1 partials (bank-conflict-free)

    // --- softmax: one pixel per thread, tid<32 ---
    if (tid < SCH_) {
        const float4* sp = (const float4*)(score + (size_t)(b * S_ + s0 + tid) * KC_);
        const float4 w0 = sp[0], w1 = sp[1], w2 = sp[2];
        float x[KC_] = {w0.x, w0.y, w0.z, w0.w, w1.x, w1.y, w1.z, w1.w,
                        w2.x, w2.y, w2.z, w2.w};
        float m = x[0];
        #pragma unroll
        for (int k = 1; k < KC_; k++) m = fmaxf(m, x[k]);
        float sum = 0.f;
        #pragma unroll
        for (int k = 0; k < KC_; k++) { x[k] = __expf(x[k] - m); sum += x[k]; }
        const float inv = 1.0f / sum;
        #pragma unroll
        for (int k = 0; k < KC_; k++) A[tid][k] = x[k] * inv;
    }
    __syncthreads();

    if (tid < K_) {
        float v = 0.f;
        #pragma unroll
        for (int s = 0; s < SCH_; s++) v += A[s][tid];
        asum_part[(b * CH_ + c) * K_ + tid] = v;
    }

    // --- accumulate: 16 pixels per thread (parity-split) ---
    float acc[K_][4];
    #pragma unroll
    for (int k = 0; k < K_; k++)
        acc[k][0] = acc[k][1] = acc[k][2] = acc[k][3] = 0.f;

    const float4* fp = (const float4*)(feat + (size_t)(b * S_ + s0) * D_) + col;
    #pragma unroll 8
    for (int i = 0; i < SCH_ / 2; i++) {
        const int s = 2 * i + par;
        const float4 v = fp[(size_t)s * (D_ / 4)];
        const float4 a0 = *(const float4*)(&A[s][0]);   // wave-uniform broadcast
        const float4 a1 = *(const float4*)(&A[s][4]);
        const float2 a2 = *(const float2*)(&A[s][8]);
        const float a[K_] = {a0.x, a0.y, a0.z, a0.w, a1.x, a1.y, a1.z, a1.w,
                             a2.x, a2.y};
        #pragma unroll
        for (int k = 0; k < K_; k++) {
            acc[k][0] += a[k] * v.x;
            acc[k][1] += a[k] * v.y;
            acc[k][2] += a[k] * v.z;
            acc[k][3] += a[k] * v.w;
        }
    }

    // --- combine parities via LDS, parity-0 stores ---
    if (par) {
        #pragma unroll
        for (int k = 0; k < K_; k++) {
            red[k * 4 + 0][col] = acc[k][0];
            red[k * 4 + 1][col] = acc[k][1];
            red[k * 4 + 2][col] = acc[k][2];
            red[k * 4 + 3][col] = acc[k][3];
        }
    }
    __syncthreads();
    if (!par) {
        float* pp = part + (((size_t)(b * K_) * CH_ + c) * D_) + col * 4;
        #pragma unroll
        for (int k = 0; k < K_; k++) {
            *(float4*)(pp + (size_t)k * CH_ * D_) = make_float4(
                acc[k][0] + red[k * 4 + 0][col],
                acc[k][1] + red[k * 4 + 1][col],
                acc[k][2] + red[k * 4 + 2][col],
                acc[k][3] + red[k * 4 + 3][col]);
        }
    }
}

// One block per (b,k): reduce chunks, subtract asum*cluster, L2-normalize row.
__global__ __launch_bounds__(256) void vlad_final(
    const float* __restrict__ part, const float* __restrict__ asum_part,
    const float* __restrict__ cluster, float* __restrict__ out)
{
    const int b = blockIdx.x / K_;
    const int k = blockIdx.x % K_;
    const int tid = threadIdx.x;
    const int d = tid * 2;

    const float* base = part + ((size_t)(b * K_ + k) * CH_) * D_ + d;
    float s0 = 0.f, s1 = 0.f;
    #pragma unroll 8
    for (int c = 0; c < CH_; c++) {
        const float2 v = *(const float2*)(base + (size_t)c * D_);
        s0 += v.x; s1 += v.y;
    }
    float asv = 0.f;
    #pragma unroll
    for (int c = 0; c < CH_; c++) asv += asum_part[(b * CH_ + c) * K_ + k];

    const float2 cv = *(const float2*)(cluster + (size_t)k * D_ + d);
    const float r0 = s0 - asv * cv.x;
    const float r1 = s1 - asv * cv.y;

    float sq = r0 * r0 + r1 * r1;
    #pragma unroll
    for (int off = 32; off > 0; off >>= 1) sq += __shfl_down(sq, off, 64);
    __shared__ float wsum[4];
    if ((tid & 63) == 0) wsum[tid >> 6] = sq;
    __syncthreads();
    const float tot = wsum[0] + wsum[1] + wsum[2] + wsum[3];
    const float scale = rsqrtf(fmaxf(tot, 1e-12f));

    *(float2*)(out + (size_t)(b * K_ + k) * D_ + d) =
        make_float2(r0 * scale, r1 * scale);
}

extern "C" void kernel_launch(void* const* d_in, const int* in_sizes, int n_in,
                              void* d_out, int out_size, void* d_ws, size_t ws_size,
                              hipStream_t stream) {
    const float* feat    = (const float*)d_in[0];
    const float* score   = (const float*)d_in[1];
    const float* cluster = (const float*)d_in[2];
    float* out = (float*)d_out;

    float* part      = (float*)d_ws;                       // B*K*CH*D fp32
    float* asum_part = part + (size_t)B_ * K_ * CH_ * D_;  // B*CH*K fp32

    vlad_accum<<<B_ * CH_, NT1, 0, stream>>>(feat, score, part, asum_part);
    vlad_final<<<B_ * K_, 256, 0, stream>>>(part, asum_part, cluster, out);
}

// Round 5
// 79.541 us; speedup vs baseline: 1.1192x; 1.0336x over previous
//
#include <hip/hip_runtime.h>
#include <hip/hip_bf16.h>

// VLAD pooling: B=16, S=H*W=1024, D=512, KC=12, K=10. All fp32.
// Kernel 1: grid B*CH (=256) blocks x 512 thr (4 s-parities x 128 d-cols),
//           partials part[B][K][CH][D] fp32 + asum_part[B][CH][K].
//           1 block/CU, 8 waves/CU; 61KB LDS parity-combine (free at 1 blk/CU).
// Kernel 2: grid B*K blocks x 256 thr: reduce CH, subtract asum*cluster,
//           L2-normalize, store.

#define B_   16
#define S_   1024
#define D_   512
#define KC_  12
#define K_   10
#define CH_  16            // s-chunks per batch
#define SCH_ (S_ / CH_)    // 64 pixels per chunk
#define NT1  512
#define NPAR 4             // s-parities in accum

__global__ __launch_bounds__(NT1) void vlad_accum(
    const float* __restrict__ feat, const float* __restrict__ score,
    float* __restrict__ part, float* __restrict__ asum_part)
{
    const int bid = blockIdx.x;
    const int b = bid / CH_, c = bid % CH_;
    const int s0 = c * SCH_;
    const int tid = threadIdx.x;
    const int par = tid >> 7;     // wave-pair-uniform s-parity, 0..3
    const int col = tid & 127;    // float4 group within D

    __shared__ float A[SCH_][KC_];            // softmax weights, rows 48B
    __shared__ float red[NPAR - 1][K_ * 4][128]; // parity 1..3 partials, 61KB

    // --- softmax: one pixel per thread, tid<64 (wave 0) ---
    if (tid < SCH_) {
        const float4* sp = (const float4*)(score + (size_t)(b * S_ + s0 + tid) * KC_);
        const float4 w0 = sp[0], w1 = sp[1], w2 = sp[2];
        float x[KC_] = {w0.x, w0.y, w0.z, w0.w, w1.x, w1.y, w1.z, w1.w,
                        w2.x, w2.y, w2.z, w2.w};
        float m = x[0];
        #pragma unroll
        for (int k = 1; k < KC_; k++) m = fmaxf(m, x[k]);
        float sum = 0.f;
        #pragma unroll
        for (int k = 0; k < KC_; k++) { x[k] = __expf(x[k] - m); sum += x[k]; }
        const float inv = 1.0f / sum;
        #pragma unroll
        for (int k = 0; k < KC_; k++) A[tid][k] = x[k] * inv;
    }
    __syncthreads();

    if (tid < K_) {
        float v = 0.f;
        #pragma unroll
        for (int s = 0; s < SCH_; s++) v += A[s][tid];
        asum_part[(b * CH_ + c) * K_ + tid] = v;
    }

    // --- accumulate: 16 pixels per thread (4-way parity split) ---
    float acc[K_][4];
    #pragma unroll
    for (int k = 0; k < K_; k++)
        acc[k][0] = acc[k][1] = acc[k][2] = acc[k][3] = 0.f;

    const float4* fp = (const float4*)(feat + (size_t)(b * S_ + s0) * D_) + col;
    #pragma unroll 8
    for (int i = 0; i < SCH_ / NPAR; i++) {
        const int s = NPAR * i + par;
        const float4 v = fp[(size_t)s * (D_ / 4)];
        const float4 a0 = *(const float4*)(&A[s][0]);   // uniform broadcast
        const float4 a1 = *(const float4*)(&A[s][4]);
        const float2 a2 = *(const float2*)(&A[s][8]);
        const float a[K_] = {a0.x, a0.y, a0.z, a0.w, a1.x, a1.y, a1.z, a1.w,
                             a2.x, a2.y};
        #pragma unroll
        for (int k = 0; k < K_; k++) {
            acc[k][0] += a[k] * v.x;
            acc[k][1] += a[k] * v.y;
            acc[k][2] += a[k] * v.z;
            acc[k][3] += a[k] * v.w;
        }
    }

    // --- combine parities 1..3 into parity 0 via LDS, parity-0 stores ---
    if (par) {
        float (* const r)[128] = red[par - 1];
        #pragma unroll
        for (int k = 0; k < K_; k++) {
            r[k * 4 + 0][col] = acc[k][0];
            r[k * 4 + 1][col] = acc[k][1];
            r[k * 4 + 2][col] = acc[k][2];
            r[k * 4 + 3][col] = acc[k][3];
        }
    }
    __syncthreads();
    if (!par) {
        float* pp = part + (((size_t)(b * K_) * CH_ + c) * D_) + col * 4;
        #pragma unroll
        for (int k = 0; k < K_; k++) {
            float v0 = acc[k][0], v1 = acc[k][1], v2 = acc[k][2], v3 = acc[k][3];
            #pragma unroll
            for (int p = 0; p < NPAR - 1; p++) {
                v0 += red[p][k * 4 + 0][col];
                v1 += red[p][k * 4 + 1][col];
                v2 += red[p][k * 4 + 2][col];
                v3 += red[p][k * 4 + 3][col];
            }
            *(float4*)(pp + (size_t)k * CH_ * D_) = make_float4(v0, v1, v2, v3);
        }
    }
}

// One block per (b,k): reduce chunks, subtract asum*cluster, L2-normalize row.
__global__ __launch_bounds__(256) void vlad_final(
    const float* __restrict__ part, const float* __restrict__ asum_part,
    const float* __restrict__ cluster, float* __restrict__ out)
{
    const int b = blockIdx.x / K_;
    const int k = blockIdx.x % K_;
    const int tid = threadIdx.x;
    const int d = tid * 2;

    const float* base = part + ((size_t)(b * K_ + k) * CH_) * D_ + d;
    float s0 = 0.f, s1 = 0.f;
    #pragma unroll 8
    for (int c = 0; c < CH_; c++) {
        const float2 v = *(const float2*)(base + (size_t)c * D_);
        s0 += v.x; s1 += v.y;
    }
    float asv = 0.f;
    #pragma unroll
    for (int c = 0; c < CH_; c++) asv += asum_part[(b * CH_ + c) * K_ + k];

    const float2 cv = *(const float2*)(cluster + (size_t)k * D_ + d);
    const float r0 = s0 - asv * cv.x;
    const float r1 = s1 - asv * cv.y;

    float sq = r0 * r0 + r1 * r1;
    #pragma unroll
    for (int off = 32; off > 0; off >>= 1) sq += __shfl_down(sq, off, 64);
    __shared__ float wsum[4];
    if ((tid & 63) == 0) wsum[tid >> 6] = sq;
    __syncthreads();
    const float tot = wsum[0] + wsum[1] + wsum[2] + wsum[3];
    const float scale = rsqrtf(fmaxf(tot, 1e-12f));

    *(float2*)(out + (size_t)(b * K_ + k) * D_ + d) =
        make_float2(r0 * scale, r1 * scale);
}

extern "C" void kernel_launch(void* const* d_in, const int* in_sizes, int n_in,
                              void* d_out, int out_size, void* d_ws, size_t ws_size,
                              hipStream_t stream) {
    const float* feat    = (const float*)d_in[0];
    const float* score   = (const float*)d_in[1];
    const float* cluster = (const float*)d_in[2];
    float* out = (float*)d_out;

    float* part      = (float*)d_ws;                       // B*K*CH*D fp32
    float* asum_part = part + (size_t)B_ * K_ * CH_ * D_;  // B*CH*K fp32

    vlad_accum<<<B_ * CH_, NT1, 0, stream>>>(feat, score, part, asum_part);
    vlad_final<<<B_ * K_, 256, 0, stream>>>(part, asum_part, cluster, out);
}